// Round 1
// baseline (128.609 us; speedup 1.0000x reference)
//
#include <hip/hip_runtime.h>
#include <math.h>

#define N_TOK 4096
#define DMODEL 512
#define NHEAD 8
#define DHEAD 64
#define CTX 10
#define NROW 8192  // B * N_TOK

typedef __bf16 bf16x4 __attribute__((ext_vector_type(4)));
typedef __bf16 bf16x8 __attribute__((ext_vector_type(8)));
typedef float  f32x4  __attribute__((ext_vector_type(4)));

#define GLOAD_LDS16(g, l) __builtin_amdgcn_global_load_lds(                 \
    (const __attribute__((address_space(1))) void*)(g),                     \
    (__attribute__((address_space(3))) void*)(l), 16, 0, 0)

// ---------------------------------------------------------------------------
// Merged weight transpose-convert + x fp32->bf16 convert:
//   blocks [0,128):   Wq|Wv [h][k=512][kk=64] fp32 -> Wtqv[n=1024][k=512] bf16
//   blocks [128,192): Wup [k=512][n=512] fp32     -> Wtup[n=512][k=512] bf16
//   blocks [192,448): x [8192][512] fp32          -> xb  [8192][512] bf16
// ---------------------------------------------------------------------------
__global__ __launch_bounds__(256) void conv_w(const float* __restrict__ Wq,
                                              const float* __restrict__ Wv,
                                              const float* __restrict__ Wup,
                                              const float* __restrict__ x,
                                              __bf16* __restrict__ Wtqv,
                                              __bf16* __restrict__ Wtup,
                                              __bf16* __restrict__ xb)
{
    const int tid = threadIdx.x;
    const int bid = blockIdx.x;

    if (bid >= 192) {                       // straight-through x convert
        const int b3 = bid - 192;           // 0..255, 16384 floats each
        const float* src = x + (size_t)b3 * 16384;
        __bf16* dst = xb + (size_t)b3 * 16384;
#pragma unroll
        for (int it = 0; it < 16; it++) {
            const int idx = it * 1024 + tid * 4;
            const float4 v = *(const float4*)(src + idx);
            bf16x4 o;
            o[0] = (__bf16)v.x; o[1] = (__bf16)v.y;
            o[2] = (__bf16)v.z; o[3] = (__bf16)v.w;
            *(bf16x4*)(dst + idx) = o;
        }
        return;
    }

    __shared__ float T[64][65];

    const float* src;
    __bf16* dstBase;
    int k0, rowBase, srcStride;
    if (bid < 128) {
        k0 = (bid & 7) * 64;
        const int h   = (bid >> 3) & 7;
        const int mat = bid >> 6;
        src = (mat ? Wv : Wq) + (size_t)h * DMODEL * DHEAD;
        dstBase = Wtqv;
        rowBase = mat * 512 + h * 64;
        srcStride = DHEAD;
    } else {
        const int b2 = bid - 128;
        k0 = (b2 & 7) * 64;
        const int n0 = (b2 >> 3) * 64;
        src = Wup + n0;
        dstBase = Wtup;
        rowBase = n0;
        srcStride = DMODEL;
    }

#pragma unroll
    for (int it = 0; it < 4; it++) {
        const int kr = it * 16 + (tid >> 4);
        const int c4 = (tid & 15) * 4;
        const float4 v = *(const float4*)(src + (size_t)(k0 + kr) * srcStride + c4);
        T[kr][c4 + 0] = v.x; T[kr][c4 + 1] = v.y;
        T[kr][c4 + 2] = v.z; T[kr][c4 + 3] = v.w;
    }
    __syncthreads();
    const int c   = tid >> 2;
    const int kk0 = (tid & 3) * 16;
    __bf16* dst = dstBase + (size_t)(rowBase + c) * DMODEL + k0 + kk0;
    bf16x8 o0, o1;
#pragma unroll
    for (int j = 0; j < 8; j++) o0[j] = (__bf16)T[kk0 + j][c];
#pragma unroll
    for (int j = 0; j < 8; j++) o1[j] = (__bf16)T[kk0 + 8 + j][c];
    *(bf16x8*)dst = o0;
    *(bf16x8*)(dst + 8) = o1;
}

// ---------------------------------------------------------------------------
// Stage 1: B-stationary MFMA GEMM. B panel [64 cols][512 k] staged in LDS
// ONCE (pre-swizzled source, XOR (col&7)<<4 so strided ds_read_b128 is
// conflict-free), A fragments streamed straight from global bf16 (one 16B
// load = one MFMA A-frag). K-loop: ZERO barriers, ZERO LDS writes.
// acc[4][4]: wave = 64 rows x 64 cols, block = 256 x 64. Grid 32x16 = 512
// blocks = 2/CU (64KB LDS), all co-resident. XCD swizzle: row = bid & 31
// (32 % 8 == 0 -> all 16 col-tiles of a row-panel on one XCD's L2).
// ---------------------------------------------------------------------------
__global__ __launch_bounds__(256) void gemm_qv_mfma(
    const __bf16* __restrict__ xb,
    const __bf16* __restrict__ Wt,
    __bf16* __restrict__ Qt,
    __bf16* __restrict__ Vt)
{
    __shared__ __align__(16) __bf16 Bs[64 * DMODEL];   // 64 KB, swizzled

    const int tid  = threadIdx.x;
    const int w    = tid >> 6;
    const int lane = tid & 63;
    const int lm   = lane & 15;
    const int q    = lane >> 4;
    const int bid  = blockIdx.x;
    const int row0 = (bid & 31) * 256;
    const int col0 = (bid >> 5) * 64;

    // ---- stage B panel once: wave w stages col r*4+w each round ----
#pragma unroll
    for (int r = 0; r < 16; r++) {
        const int c   = r * 4 + w;
        const int swz = (c & 7) << 4;
        const __bf16* src = Wt + (size_t)(col0 + c) * DMODEL
                          + (((lane * 16) ^ swz) >> 1);
        GLOAD_LDS16(src, Bs + (size_t)c * DMODEL);
    }

    const __bf16* gA = xb + (size_t)(row0 + w * 64 + lm) * DMODEL + q * 8;
    const char* BsB  = (const char*)Bs;
    const int swzr   = (lm & 7) << 4;
    const int bbase  = lm * 1024;

    f32x4 acc[4][4];
#pragma unroll
    for (int i = 0; i < 4; i++)
#pragma unroll
        for (int j = 0; j < 4; j++) acc[i][j] = (f32x4){0.f, 0.f, 0.f, 0.f};

    __syncthreads();   // compiler drains vmcnt(0) here: B panel resident

#pragma unroll 4
    for (int kk = 0; kk < 16; kk++) {
        bf16x8 af[4], bfr[4];
#pragma unroll
        for (int mi = 0; mi < 4; mi++)
            af[mi] = *(const bf16x8*)(gA + (size_t)mi * 16 * DMODEL + kk * 32);
        const int off = (kk * 64 + q * 16) ^ swzr;
#pragma unroll
        for (int ni = 0; ni < 4; ni++)
            bfr[ni] = *(const bf16x8*)(BsB + ni * 16 * 1024 + bbase + off);
#pragma unroll
        for (int mi = 0; mi < 4; mi++)
#pragma unroll
            for (int ni = 0; ni < 4; ni++)
                acc[mi][ni] = __builtin_amdgcn_mfma_f32_16x16x32_bf16(
                    af[mi], bfr[ni], acc[mi][ni], 0, 0, 0);
    }

    // Epilogue: bf16 dim-major scatter [bb*512+cc][token]
#pragma unroll
    for (int ni = 0; ni < 4; ni++) {
        const int c  = col0 + ni * 16 + lm;
        const int cc = c & 511;
        __bf16* outB = (c < 512 ? Qt : Vt);
#pragma unroll
        for (int mi = 0; mi < 4; mi++) {
            const int m  = row0 + w * 64 + mi * 16 + q * 4;
            const int bb = m >> 12;
            const int nt = m & (N_TOK - 1);
            bf16x4 o;
            o[0] = (__bf16)acc[mi][ni][0];
            o[1] = (__bf16)acc[mi][ni][1];
            o[2] = (__bf16)acc[mi][ni][2];
            o[3] = (__bf16)acc[mi][ni][3];
            *(bf16x4*)(outB + ((size_t)(bb * 512 + cc)) * N_TOK + nt) = o;
        }
    }
}

// ---------------------------------------------------------------------------
// Stage 2: banded attention (unchanged from round 10).
// ---------------------------------------------------------------------------
#define VSTRIDE 97
__global__ __launch_bounds__(256) void attn_band(
    const __bf16* __restrict__ Qt,
    const __bf16* __restrict__ Vt,
    __bf16* __restrict__ Hb16)
{
    __shared__ float Vs[64 * VSTRIDE];   // 24,832 B

    const int tid  = threadIdx.x;
    const int bh   = blockIdx.x >> 6;
    const int tile = blockIdx.x & 63;
    const int i0   = tile * 64;
    const int b    = bh >> 3;
    const int h    = bh & 7;

    const __bf16* vband = Vt + (size_t)bh * DHEAD * N_TOK;
    const int tok0 = i0 - 16;
#pragma unroll
    for (int it = 0; it < 3; it++) {
        const int idx = it * 256 + tid;        // 0..767
        const int k   = idx / 12;              // dim
        const int s8  = idx - k * 12;          // 8-token chunk, 8-aligned
        const int tokg = tok0 + s8 * 8;
        const int tokc = min(max(tokg, 0), N_TOK - 8);
        const bf16x8 v = *(const bf16x8*)(vband + (size_t)k * N_TOK + tokc);
        float* dst = &Vs[k * VSTRIDE + s8 * 8];
#pragma unroll
        for (int e = 0; e < 8; e++) dst[e] = (float)v[e];
    }

    const int lane = tid & 63;
    const int wv   = tid >> 6;
    const int il   = lane & 15;
    const int p    = lane >> 4;
    const int i    = i0 + wv * 16 + il;
    const int slot0 = wv * 16 + il + 6;        // slot of tap d=0 (j=i-10)

    const __bf16* qbase = Qt + ((size_t)bh * DHEAD + p * 16) * N_TOK;
    float qv[16];
#pragma unroll
    for (int k = 0; k < 16; k++) qv[k] = (float)qbase[(size_t)k * N_TOK + i];

    __syncthreads();

    float c[16];
#pragma unroll
    for (int k = 0; k < 16; k++) c[k] = 0.f;
    float Z = 0.f;

#pragma unroll 3
    for (int d = 0; d < 2 * CTX + 1; d++) {
        const float* vrow = &Vs[p * 16 * VSTRIDE + slot0 + d];
        float v[16];
#pragma unroll
        for (int k = 0; k < 16; k++) v[k] = vrow[k * VSTRIDE];
        float s = 0.f;
#pragma unroll
        for (int k = 0; k < 16; k++) s += qv[k] * v[k];
        s += __shfl_xor(s, 16, 64);
        s += __shfl_xor(s, 32, 64);

        const int j = i + d - CTX;
        const bool valid = (d != CTX) && (j >= 0) && (j < N_TOK);
        const float w = valid ? __expf(s * 0.0625f) : 0.f;
        Z += w;
#pragma unroll
        for (int k = 0; k < 16; k++) c[k] += w * v[k];
    }

    const float inv = 1.f / Z;
    __bf16* dst = Hb16 + ((size_t)(b * N_TOK + i)) * DMODEL + h * DHEAD + p * 16;
    bf16x8 o0, o1;
#pragma unroll
    for (int k = 0; k < 8; k++) o0[k] = (__bf16)(c[k] * inv);
#pragma unroll
    for (int k = 0; k < 8; k++) o1[k] = (__bf16)(c[8 + k] * inv);
    *(bf16x8*)dst = o0;
    *(bf16x8*)(dst + 8) = o1;
}

// ---------------------------------------------------------------------------
// Stage 3: B-stationary MFMA GEMM, same structure as stage 1.
// Grid 32x8 = 256 blocks (1/CU). fp32 output scatter.
// ---------------------------------------------------------------------------
__global__ __launch_bounds__(256) void gemm_out_mfma(
    const __bf16* __restrict__ Hb,
    const __bf16* __restrict__ Wt,
    float* __restrict__ out)
{
    __shared__ __align__(16) __bf16 Bs[64 * DMODEL];   // 64 KB

    const int tid  = threadIdx.x;
    const int w    = tid >> 6;
    const int lane = tid & 63;
    const int lm   = lane & 15;
    const int q    = lane >> 4;
    const int bid  = blockIdx.x;
    const int row0 = (bid & 31) * 256;
    const int col0 = (bid >> 5) * 64;

#pragma unroll
    for (int r = 0; r < 16; r++) {
        const int c   = r * 4 + w;
        const int swz = (c & 7) << 4;
        const __bf16* src = Wt + (size_t)(col0 + c) * DMODEL
                          + (((lane * 16) ^ swz) >> 1);
        GLOAD_LDS16(src, Bs + (size_t)c * DMODEL);
    }

    const __bf16* gA = Hb + (size_t)(row0 + w * 64 + lm) * DMODEL + q * 8;
    const char* BsB  = (const char*)Bs;
    const int swzr   = (lm & 7) << 4;
    const int bbase  = lm * 1024;

    f32x4 acc[4][4];
#pragma unroll
    for (int i = 0; i < 4; i++)
#pragma unroll
        for (int j = 0; j < 4; j++) acc[i][j] = (f32x4){0.f, 0.f, 0.f, 0.f};

    __syncthreads();

#pragma unroll 4
    for (int kk = 0; kk < 16; kk++) {
        bf16x8 af[4], bfr[4];
#pragma unroll
        for (int mi = 0; mi < 4; mi++)
            af[mi] = *(const bf16x8*)(gA + (size_t)mi * 16 * DMODEL + kk * 32);
        const int off = (kk * 64 + q * 16) ^ swzr;
#pragma unroll
        for (int ni = 0; ni < 4; ni++)
            bfr[ni] = *(const bf16x8*)(BsB + ni * 16 * 1024 + bbase + off);
#pragma unroll
        for (int mi = 0; mi < 4; mi++)
#pragma unroll
            for (int ni = 0; ni < 4; ni++)
                acc[mi][ni] = __builtin_amdgcn_mfma_f32_16x16x32_bf16(
                    af[mi], bfr[ni], acc[mi][ni], 0, 0, 0);
    }

#pragma unroll
    for (int mi = 0; mi < 4; mi++) {
        const int m0 = row0 + w * 64 + mi * 16 + q * 4;
#pragma unroll
        for (int ni = 0; ni < 4; ni++) {
            const int n = col0 + ni * 16 + lm;
#pragma unroll
            for (int r = 0; r < 4; r++)
                out[(size_t)(m0 + r) * DMODEL + n] = acc[mi][ni][r];
        }
    }
}

// ---------------------------------------------------------------------------
extern "C" void kernel_launch(void* const* d_in, const int* in_sizes, int n_in,
                              void* d_out, int out_size, void* d_ws, size_t ws_size,
                              hipStream_t stream)
{
    const float* x   = (const float*)d_in[0];
    const float* Wq  = (const float*)d_in[1];
    const float* Wv  = (const float*)d_in[2];
    const float* Wup = (const float*)d_in[3];
    float* out = (float*)d_out;

    const size_t QV = (size_t)2 * NHEAD * N_TOK * DHEAD;   // 4,194,304 elems
    __bf16* Qt   = (__bf16*)d_ws;                          // 8.39 MB
    __bf16* Vt   = Qt + QV;                                // 8.39 MB
    __bf16* Hb16 = Vt + QV;                                // 8.39 MB
    __bf16* Wtqv = Hb16 + (size_t)NROW * DMODEL;           // 1.05 MB
    __bf16* Wtup = Wtqv + (size_t)1024 * DMODEL;           // 0.52 MB
    __bf16* xb   = Wtup + (size_t)512 * DMODEL;            // 8.39 MB

    dim3 blk(256);
    conv_w       <<<dim3(448),  blk, 0, stream>>>(Wq, Wv, Wup, x, Wtqv, Wtup, xb);
    gemm_qv_mfma <<<dim3(512),  blk, 0, stream>>>(xb, Wtqv, Qt, Vt);
    attn_band    <<<dim3(1024), blk, 0, stream>>>(Qt, Vt, Hb16);
    gemm_out_mfma<<<dim3(256),  blk, 0, stream>>>(Hb16, Wtup, out);
}

// Round 2
// 114.913 us; speedup vs baseline: 1.1192x; 1.1192x over previous
//
#include <hip/hip_runtime.h>
#include <math.h>

#define N_TOK 4096
#define DMODEL 512
#define NHEAD 8
#define DHEAD 64
#define CTX 10
#define NROW 8192  // B * N_TOK

typedef __bf16 bf16x4 __attribute__((ext_vector_type(4)));
typedef __bf16 bf16x8 __attribute__((ext_vector_type(8)));
typedef float  f32x4  __attribute__((ext_vector_type(4)));

#define GLOAD_LDS16(g, l) __builtin_amdgcn_global_load_lds(                 \
    (const __attribute__((address_space(1))) void*)(g),                     \
    (__attribute__((address_space(3))) void*)(l), 16, 0, 0)

// ---------------------------------------------------------------------------
// Merged weight transpose-convert + x fp32->bf16 convert:
//   blocks [0,128):   Wq|Wv [h][k=512][kk=64] fp32 -> Wtqv[n=1024][k=512] bf16
//   blocks [128,192): Wup [k=512][n=512] fp32     -> Wtup[n=512][k=512] bf16
//   blocks [192,448): x [8192][512] fp32          -> xb  [8192][512] bf16
// ---------------------------------------------------------------------------
__global__ __launch_bounds__(256) void conv_w(const float* __restrict__ Wq,
                                              const float* __restrict__ Wv,
                                              const float* __restrict__ Wup,
                                              const float* __restrict__ x,
                                              __bf16* __restrict__ Wtqv,
                                              __bf16* __restrict__ Wtup,
                                              __bf16* __restrict__ xb)
{
    const int tid = threadIdx.x;
    const int bid = blockIdx.x;

    if (bid >= 192) {                       // straight-through x convert
        const int b3 = bid - 192;           // 0..255, 16384 floats each
        const float* src = x + (size_t)b3 * 16384;
        __bf16* dst = xb + (size_t)b3 * 16384;
#pragma unroll
        for (int it = 0; it < 16; it++) {
            const int idx = it * 1024 + tid * 4;
            const float4 v = *(const float4*)(src + idx);
            bf16x4 o;
            o[0] = (__bf16)v.x; o[1] = (__bf16)v.y;
            o[2] = (__bf16)v.z; o[3] = (__bf16)v.w;
            *(bf16x4*)(dst + idx) = o;
        }
        return;
    }

    __shared__ float T[64][65];

    const float* src;
    __bf16* dstBase;
    int k0, rowBase, srcStride;
    if (bid < 128) {
        k0 = (bid & 7) * 64;
        const int h   = (bid >> 3) & 7;
        const int mat = bid >> 6;
        src = (mat ? Wv : Wq) + (size_t)h * DMODEL * DHEAD;
        dstBase = Wtqv;
        rowBase = mat * 512 + h * 64;
        srcStride = DHEAD;
    } else {
        const int b2 = bid - 128;
        k0 = (b2 & 7) * 64;
        const int n0 = (b2 >> 3) * 64;
        src = Wup + n0;
        dstBase = Wtup;
        rowBase = n0;
        srcStride = DMODEL;
    }

#pragma unroll
    for (int it = 0; it < 4; it++) {
        const int kr = it * 16 + (tid >> 4);
        const int c4 = (tid & 15) * 4;
        const float4 v = *(const float4*)(src + (size_t)(k0 + kr) * srcStride + c4);
        T[kr][c4 + 0] = v.x; T[kr][c4 + 1] = v.y;
        T[kr][c4 + 2] = v.z; T[kr][c4 + 3] = v.w;
    }
    __syncthreads();
    const int c   = tid >> 2;
    const int kk0 = (tid & 3) * 16;
    __bf16* dst = dstBase + (size_t)(rowBase + c) * DMODEL + k0 + kk0;
    bf16x8 o0, o1;
#pragma unroll
    for (int j = 0; j < 8; j++) o0[j] = (__bf16)T[kk0 + j][c];
#pragma unroll
    for (int j = 0; j < 8; j++) o1[j] = (__bf16)T[kk0 + 8 + j][c];
    *(bf16x8*)dst = o0;
    *(bf16x8*)(dst + 8) = o1;
}

// ---------------------------------------------------------------------------
// Stage 1: MFMA GEMM  xb[8192x512]bf16 @ Wt^T -> Qt, Vt bf16 dim-major.
// Round-0 structure (128x64 tile, 1024 blocks, 4/CU, barriered LDS staging)
// with two changes:
//   * A staged via global_load_lds from pre-converted bf16 xb (no VGPR
//     roundtrip, no fp32->bf16 cvt, no ds_write in the K-loop).
//   * BK=64: halves barrier pairs (16 -> 8). 128B LDS rows would put 16
//     lanes on one bank-quad, so XOR-swizzle: source col ((l&7)^(l>>3))*8,
//     linear GLOAD dest, read slot (kk2*4+q)^(lm&7). LDS[r][s]=G[r][s^(r&7)]
//     both sides -> uniform 8 lanes/quad (optimal).
// XCD swizzle: row = bid & 63 (all 16 col-tiles of a row-panel on one XCD).
// ---------------------------------------------------------------------------
__global__ __launch_bounds__(256) void gemm_qv_mfma(
    const __bf16* __restrict__ xb,
    const __bf16* __restrict__ Wt,
    __bf16* __restrict__ Qt,
    __bf16* __restrict__ Vt)
{
    __shared__ __align__(16) __bf16 As[128 * 64];   // 16 KB
    __shared__ __align__(16) __bf16 Bs[64 * 64];    // 8 KB

    const int tid  = threadIdx.x;
    const int w    = tid >> 6;
    const int lane = tid & 63;
    const int lm   = lane & 15;
    const int q    = lane >> 4;
    const int bid  = blockIdx.x;
    const int row0 = (bid & 63) * 128;     // XCD-swizzled
    const int col0 = (bid >> 6) * 64;      // 16 col-tiles

    // pre-swizzled staging source: lane l -> row +(l>>3), col ((l&7)^(l>>3))*8
    const int sxr = lane >> 3;
    const int sxc = ((lane & 7) ^ sxr) * 8;
    const __bf16* gA = xb + (size_t)(row0 + w * 32 + sxr) * DMODEL + sxc;
    const __bf16* gB = Wt + (size_t)(col0 + w * 16 + sxr) * DMODEL + sxc;
    __bf16* lA = As + w * 32 * 64;         // wave-uniform LDS bases
    __bf16* lB = Bs + w * 16 * 64;

    const int off0 = ((q ^ (lm & 7)) * 8);             // kk2=0 read slot
    // kk2=1 slot = off0 ^ 32  (since (4+q)^r == (q^r)^4 for q<4)

    f32x4 acc[2][4];
#pragma unroll
    for (int i = 0; i < 2; i++)
#pragma unroll
        for (int j = 0; j < 4; j++) acc[i][j] = (f32x4){0.f, 0.f, 0.f, 0.f};

    for (int k0 = 0; k0 < DMODEL; k0 += 64) {
        __syncthreads();
#pragma unroll
        for (int g = 0; g < 4; g++)
            GLOAD_LDS16(gA + (size_t)g * 8 * DMODEL, lA + g * 512);
#pragma unroll
        for (int g = 0; g < 2; g++)
            GLOAD_LDS16(gB + (size_t)g * 8 * DMODEL, lB + g * 512);
        gA += 64; gB += 64;
        __syncthreads();

        bf16x8 af[2][2], bfr[4][2];
#pragma unroll
        for (int mi = 0; mi < 2; mi++) {
            const int r = (w * 32 + mi * 16 + lm) * 64;
            af[mi][0] = *(const bf16x8*)&As[r + off0];
            af[mi][1] = *(const bf16x8*)&As[r + (off0 ^ 32)];
        }
#pragma unroll
        for (int ni = 0; ni < 4; ni++) {
            const int r = (ni * 16 + lm) * 64;
            bfr[ni][0] = *(const bf16x8*)&Bs[r + off0];
            bfr[ni][1] = *(const bf16x8*)&Bs[r + (off0 ^ 32)];
        }
#pragma unroll
        for (int kk2 = 0; kk2 < 2; kk2++)
#pragma unroll
            for (int mi = 0; mi < 2; mi++)
#pragma unroll
                for (int ni = 0; ni < 4; ni++)
                    acc[mi][ni] = __builtin_amdgcn_mfma_f32_16x16x32_bf16(
                        af[mi][kk2], bfr[ni][kk2], acc[mi][ni], 0, 0, 0);
    }

    // Epilogue: bf16 dim-major scatter [bb*512+cc][token]
#pragma unroll
    for (int ni = 0; ni < 4; ni++) {
        const int c  = col0 + ni * 16 + lm;
        const int cc = c & 511;
        __bf16* outB = (c < 512 ? Qt : Vt);
#pragma unroll
        for (int mi = 0; mi < 2; mi++) {
            const int m  = row0 + w * 32 + mi * 16 + q * 4;
            const int bb = m >> 12;
            const int nt = m & (N_TOK - 1);
            bf16x4 o;
            o[0] = (__bf16)acc[mi][ni][0];
            o[1] = (__bf16)acc[mi][ni][1];
            o[2] = (__bf16)acc[mi][ni][2];
            o[3] = (__bf16)acc[mi][ni][3];
            *(bf16x4*)(outB + ((size_t)(bb * 512 + cc)) * N_TOK + nt) = o;
        }
    }
}

// ---------------------------------------------------------------------------
// Stage 2: banded attention (unchanged).
// ---------------------------------------------------------------------------
#define VSTRIDE 97
__global__ __launch_bounds__(256) void attn_band(
    const __bf16* __restrict__ Qt,
    const __bf16* __restrict__ Vt,
    __bf16* __restrict__ Hb16)
{
    __shared__ float Vs[64 * VSTRIDE];   // 24,832 B

    const int tid  = threadIdx.x;
    const int bh   = blockIdx.x >> 6;
    const int tile = blockIdx.x & 63;
    const int i0   = tile * 64;
    const int b    = bh >> 3;
    const int h    = bh & 7;

    const __bf16* vband = Vt + (size_t)bh * DHEAD * N_TOK;
    const int tok0 = i0 - 16;
#pragma unroll
    for (int it = 0; it < 3; it++) {
        const int idx = it * 256 + tid;        // 0..767
        const int k   = idx / 12;              // dim
        const int s8  = idx - k * 12;          // 8-token chunk, 8-aligned
        const int tokg = tok0 + s8 * 8;
        const int tokc = min(max(tokg, 0), N_TOK - 8);
        const bf16x8 v = *(const bf16x8*)(vband + (size_t)k * N_TOK + tokc);
        float* dst = &Vs[k * VSTRIDE + s8 * 8];
#pragma unroll
        for (int e = 0; e < 8; e++) dst[e] = (float)v[e];
    }

    const int lane = tid & 63;
    const int wv   = tid >> 6;
    const int il   = lane & 15;
    const int p    = lane >> 4;
    const int i    = i0 + wv * 16 + il;
    const int slot0 = wv * 16 + il + 6;        // slot of tap d=0 (j=i-10)

    const __bf16* qbase = Qt + ((size_t)bh * DHEAD + p * 16) * N_TOK;
    float qv[16];
#pragma unroll
    for (int k = 0; k < 16; k++) qv[k] = (float)qbase[(size_t)k * N_TOK + i];

    __syncthreads();

    float c[16];
#pragma unroll
    for (int k = 0; k < 16; k++) c[k] = 0.f;
    float Z = 0.f;

#pragma unroll 3
    for (int d = 0; d < 2 * CTX + 1; d++) {
        const float* vrow = &Vs[p * 16 * VSTRIDE + slot0 + d];
        float v[16];
#pragma unroll
        for (int k = 0; k < 16; k++) v[k] = vrow[k * VSTRIDE];
        float s = 0.f;
#pragma unroll
        for (int k = 0; k < 16; k++) s += qv[k] * v[k];
        s += __shfl_xor(s, 16, 64);
        s += __shfl_xor(s, 32, 64);

        const int j = i + d - CTX;
        const bool valid = (d != CTX) && (j >= 0) && (j < N_TOK);
        const float w = valid ? __expf(s * 0.0625f) : 0.f;
        Z += w;
#pragma unroll
        for (int k = 0; k < 16; k++) c[k] += w * v[k];
    }

    const float inv = 1.f / Z;
    __bf16* dst = Hb16 + ((size_t)(b * N_TOK + i)) * DMODEL + h * DHEAD + p * 16;
    bf16x8 o0, o1;
#pragma unroll
    for (int k = 0; k < 8; k++) o0[k] = (__bf16)(c[k] * inv);
#pragma unroll
    for (int k = 0; k < 8; k++) o1[k] = (__bf16)(c[8 + k] * inv);
    *(bf16x8*)dst = o0;
    *(bf16x8*)(dst + 8) = o1;
}

// ---------------------------------------------------------------------------
// Stage 3: MFMA GEMM  Hb16[8192x512] @ Wup -> out fp32 [8192x512].
// Same BK=64 swizzled-GLOAD structure as stage 1. 512 blocks, 2/CU.
// ---------------------------------------------------------------------------
__global__ __launch_bounds__(256) void gemm_out_mfma(
    const __bf16* __restrict__ Hb,
    const __bf16* __restrict__ Wt,
    float* __restrict__ out)
{
    __shared__ __align__(16) __bf16 As[128 * 64];
    __shared__ __align__(16) __bf16 Bs[64 * 64];

    const int tid  = threadIdx.x;
    const int w    = tid >> 6;
    const int lane = tid & 63;
    const int lm   = lane & 15;
    const int q    = lane >> 4;
    const int bid  = blockIdx.x;
    const int row0 = (bid & 63) * 128;     // XCD-swizzled
    const int col0 = (bid >> 6) * 64;      // 8 col-tiles

    const int sxr = lane >> 3;
    const int sxc = ((lane & 7) ^ sxr) * 8;
    const __bf16* gA = Hb + (size_t)(row0 + w * 32 + sxr) * DMODEL + sxc;
    const __bf16* gB = Wt + (size_t)(col0 + w * 16 + sxr) * DMODEL + sxc;
    __bf16* lA = As + w * 32 * 64;
    __bf16* lB = Bs + w * 16 * 64;

    const int off0 = ((q ^ (lm & 7)) * 8);

    f32x4 acc[2][4];
#pragma unroll
    for (int i = 0; i < 2; i++)
#pragma unroll
        for (int j = 0; j < 4; j++) acc[i][j] = (f32x4){0.f, 0.f, 0.f, 0.f};

    for (int k0 = 0; k0 < DMODEL; k0 += 64) {
        __syncthreads();
#pragma unroll
        for (int g = 0; g < 4; g++)
            GLOAD_LDS16(gA + (size_t)g * 8 * DMODEL, lA + g * 512);
#pragma unroll
        for (int g = 0; g < 2; g++)
            GLOAD_LDS16(gB + (size_t)g * 8 * DMODEL, lB + g * 512);
        gA += 64; gB += 64;
        __syncthreads();

        bf16x8 af[2][2], bfr[4][2];
#pragma unroll
        for (int mi = 0; mi < 2; mi++) {
            const int r = (w * 32 + mi * 16 + lm) * 64;
            af[mi][0] = *(const bf16x8*)&As[r + off0];
            af[mi][1] = *(const bf16x8*)&As[r + (off0 ^ 32)];
        }
#pragma unroll
        for (int ni = 0; ni < 4; ni++) {
            const int r = (ni * 16 + lm) * 64;
            bfr[ni][0] = *(const bf16x8*)&Bs[r + off0];
            bfr[ni][1] = *(const bf16x8*)&Bs[r + (off0 ^ 32)];
        }
#pragma unroll
        for (int kk2 = 0; kk2 < 2; kk2++)
#pragma unroll
            for (int mi = 0; mi < 2; mi++)
#pragma unroll
                for (int ni = 0; ni < 4; ni++)
                    acc[mi][ni] = __builtin_amdgcn_mfma_f32_16x16x32_bf16(
                        af[mi][kk2], bfr[ni][kk2], acc[mi][ni], 0, 0, 0);
    }

#pragma unroll
    for (int mi = 0; mi < 2; mi++) {
        const int m0 = row0 + w * 32 + mi * 16 + q * 4;
#pragma unroll
        for (int ni = 0; ni < 4; ni++) {
            const int n = col0 + ni * 16 + lm;
#pragma unroll
            for (int r = 0; r < 4; r++)
                out[(size_t)(m0 + r) * DMODEL + n] = acc[mi][ni][r];
        }
    }
}

// ---------------------------------------------------------------------------
extern "C" void kernel_launch(void* const* d_in, const int* in_sizes, int n_in,
                              void* d_out, int out_size, void* d_ws, size_t ws_size,
                              hipStream_t stream)
{
    const float* x   = (const float*)d_in[0];
    const float* Wq  = (const float*)d_in[1];
    const float* Wv  = (const float*)d_in[2];
    const float* Wup = (const float*)d_in[3];
    float* out = (float*)d_out;

    const size_t QV = (size_t)2 * NHEAD * N_TOK * DHEAD;   // 4,194,304 elems
    __bf16* Qt   = (__bf16*)d_ws;                          // 8.39 MB
    __bf16* Vt   = Qt + QV;                                // 8.39 MB
    __bf16* Hb16 = Vt + QV;                                // 8.39 MB
    __bf16* Wtqv = Hb16 + (size_t)NROW * DMODEL;           // 1.05 MB
    __bf16* Wtup = Wtqv + (size_t)1024 * DMODEL;           // 0.52 MB
    __bf16* xb   = Wtup + (size_t)512 * DMODEL;            // 8.39 MB

    dim3 blk(256);
    conv_w       <<<dim3(448),  blk, 0, stream>>>(Wq, Wv, Wup, x, Wtqv, Wtup, xb);
    gemm_qv_mfma <<<dim3(1024), blk, 0, stream>>>(xb, Wtqv, Qt, Vt);
    attn_band    <<<dim3(1024), blk, 0, stream>>>(Qt, Vt, Hb16);
    gemm_out_mfma<<<dim3(512),  blk, 0, stream>>>(Hb16, Wtup, out);
}